// Round 3
// baseline (174.403 us; speedup 1.0000x reference)
//
#include <hip/hip_runtime.h>

#define WIN 7
#define OUT_W 126
#define OUT_H 16
#define IN_W 132            // OUT_W + 6
#define IN_H 22             // OUT_H + 6
#define APITCH 532          // words per LDS row: 132 cols * 4 stats + 4 pad (532%32=20 -> 2-way banks)
#define H 384
#define W 384
#define OH 378
#define OW 378
#define NIMG 128
#define TX 3                // 3*126 = 378 exact
#define TY 24               // 23*16=368, last tile 10 rows
#define NBLK (TX * TY * NIMG)   // 9216

__device__ __forceinline__ float wave_reduce(float v) {
#pragma unroll
    for (int off = 32; off > 0; off >>= 1) v += __shfl_down(v, off, 64);
    return v;
}

__global__ __launch_bounds__(256, 4) void ssim_main(const float* __restrict__ pred,
                                                    const float* __restrict__ act,
                                                    float* __restrict__ partials) {
    // One AoS array: per (row, col) a float4 (Sx, Sy, Sxx+Syy, Sxy).
    // +4 words so group-15's 14th quad at row 15 stays in-bounds (word 8515 < 8516).
    __shared__ __align__(16) float A[OUT_H * APITCH + 4];
    __shared__ float red[4];

    const int t = threadIdx.x;
    const int x0 = blockIdx.x * OUT_W;
    const int y0 = blockIdx.y * OUT_H;
    const size_t base = (size_t)blockIdx.z * H * W;

    // ---------- vertical pass: sliding 7-row sums, 4 fused stats ----------
    if (t < IN_W) {
        const int col = x0 + t;                  // <= 383 always (252+131=383)
        const float* xc = pred + base + col;
        const float* yc = act + base + col;
        float xv[IN_H], yv[IN_H];
#pragma unroll
        for (int i = 0; i < IN_H; ++i) {
            const int row = y0 + i;
            const bool ok = row < H;             // only last y-tile clips
            xv[i] = ok ? xc[(size_t)row * W] : 0.f;
            yv[i] = ok ? yc[(size_t)row * W] : 0.f;
        }
        float sx = 0.f, sy = 0.f, sq = 0.f, sxy = 0.f;
#pragma unroll
        for (int k = 0; k < WIN; ++k) {
            sx += xv[k];
            sy += yv[k];
            sq = fmaf(xv[k], xv[k], fmaf(yv[k], yv[k], sq));
            sxy = fmaf(xv[k], yv[k], sxy);
        }
        float* ap = &A[t * 4];
        *(float4*)ap = make_float4(sx, sy, sq, sxy);
#pragma unroll
        for (int r = 1; r < OUT_H; ++r) {
            const float xn = xv[r + 6], yn = yv[r + 6];
            const float xo = xv[r - 1], yo = yv[r - 1];
            sx += xn - xo;
            sy += yn - yo;
            sq = fmaf(xn, xn, fmaf(yn, yn, fmaf(-xo, xo, fmaf(-yo, yo, sq))));
            sxy = fmaf(xn, yn, fmaf(-xo, yo, sxy));
            *(float4*)(ap + r * APITCH) = make_float4(sx, sy, sq, sxy);
        }
    }
    __syncthreads();

    // ---------- horizontal pass: 14 quads, 4 sliding sums, SSIM ----------
    const int r = t & 15;        // tile row, exact (OUT_H==16)
    const int g = t >> 4;        // column group: outputs g*8 .. g*8+7
    const int c0 = g * 8;

    const float C1B = 0.2401f;   // C1 * 49^2
    const float C2B = 2.1168f;   // C2 * 48*49

    const float4* qp = (const float4*)&A[r * APITCH + c0 * 4];
    float4 q[14];
#pragma unroll
    for (int k = 0; k < 14; ++k) q[k] = qp[k];   // unconditional: garbage rows masked below

    float acc = 0.f;
    if (y0 + r < OH) {
        float Sx = 0.f, Sy = 0.f, Sq = 0.f, Sxy = 0.f;
#pragma unroll
        for (int k = 0; k < WIN - 1; ++k) {
            Sx += q[k].x; Sy += q[k].y; Sq += q[k].z; Sxy += q[k].w;
        }
#pragma unroll
        for (int j = 0; j < 8; ++j) {
            Sx += q[j + 6].x; Sy += q[j + 6].y; Sq += q[j + 6].z; Sxy += q[j + 6].w;

            const float p = Sx * Sy;
            const float qq = fmaf(Sx, Sx, Sy * Sy);
            const float n1 = fmaf(2.f, p, C1B);
            const float n2 = fmaf(98.f, Sxy, fmaf(-2.f, p, C2B));
            const float d1 = qq + C1B;
            const float d2 = fmaf(49.f, Sq, C2B - qq);
            const float s = (n1 * n2) * __builtin_amdgcn_rcpf(d1 * d2);
            // only g==15, j>=6 is invalid (126 = 15*8 + 6); garbage may be NaN -> select, don't scale
            acc = (c0 + j < OUT_W) ? acc + s : acc;

            Sx -= q[j].x; Sy -= q[j].y; Sq -= q[j].z; Sxy -= q[j].w;
        }
    }

    // ---------- block reduction ----------
    const float wsum = wave_reduce(acc);
    if ((t & 63) == 0) red[t >> 6] = wsum;
    __syncthreads();
    if (t == 0) {
        partials[blockIdx.x + TX * (blockIdx.y + TY * blockIdx.z)] =
            red[0] + red[1] + red[2] + red[3];
    }
}

__global__ __launch_bounds__(1024) void ssim_finalize(const float* __restrict__ partials,
                                                      float* __restrict__ out) {
    __shared__ double red[1024];
    const int t = threadIdx.x;
    double s = 0.0;
    for (int i = t; i < NBLK; i += 1024) s += (double)partials[i];
    red[t] = s;
    __syncthreads();
#pragma unroll
    for (int off = 512; off > 0; off >>= 1) {
        if (t < off) red[t] += red[t + off];
        __syncthreads();
    }
    if (t == 0) out[0] = (float)(red[0] / ((double)NIMG * OH * OW));
}

extern "C" void kernel_launch(void* const* d_in, const int* in_sizes, int n_in,
                              void* d_out, int out_size, void* d_ws, size_t ws_size,
                              hipStream_t stream) {
    const float* pred = (const float*)d_in[0];
    const float* act  = (const float*)d_in[1];
    float* partials = (float*)d_ws;              // NBLK floats, fully overwritten each call
    dim3 grid(TX, TY, NIMG);
    ssim_main<<<grid, 256, 0, stream>>>(pred, act, partials);
    ssim_finalize<<<1, 1024, 0, stream>>>(partials, (float*)d_out);
}

// Round 4
// 166.854 us; speedup vs baseline: 1.0452x; 1.0452x over previous
//
#include <hip/hip_runtime.h>

#define WIN 7
#define OUT_W 126
#define OUT_H 15
#define IN_W 132    // OUT_W + 6
#define IN_H 21     // OUT_H + 6
#define PITCH 132   // LDS row pitch in words (R2-measured cheap patterns; keep verbatim)
#define AELEM (OUT_H * PITCH)   // 1980 floats per array
#define H 384
#define W 384
#define OH 378
#define OW 378
#define NIMG 128
#define TX 3        // 3*126 = 378 exactly
#define TY 26       // 25*15=375, last tile 3 rows
#define NBLK (TX * TY * NIMG)   // 9984

__device__ __forceinline__ float wave_reduce(float v) {
#pragma unroll
    for (int off = 32; off > 0; off >>= 1) v += __shfl_down(v, off, 64);
    return v;
}

__global__ __launch_bounds__(256, 5) void ssim_main(const float* __restrict__ pred,
                                                    const float* __restrict__ act,
                                                    float* __restrict__ partials) {
    // 4 SoA arrays (sx, sy, sxx+syy, sxy), row-major [OUT_H][PITCH].
    // +16 pad words: group-15 b128 overread of last array (masked, must not fault).
    // 4*1980*4 = 31.7 KB -> 5 blocks/CU.
    __shared__ __align__(16) float cs[4 * AELEM + 16];
    __shared__ float red[4];

    const int t = threadIdx.x;
    const int x0 = blockIdx.x * OUT_W;
    const int y0 = blockIdx.y * OUT_H;
    const size_t base = (size_t)blockIdx.z * H * W;

    // ---------- vertical pass: sliding 7-row sums, 4 fused stats ----------
    if (t < IN_W) {
        const int col = x0 + t;                       // <= 383 always
        const float* xc = pred + base + col;
        const float* yc = act + base + col;
        float xv[IN_H], yv[IN_H];
#pragma unroll
        for (int i = 0; i < IN_H; ++i) {
            const int row = y0 + i;
            const bool ok = row < H;                  // only last y-tile clips
            xv[i] = ok ? xc[(size_t)row * W] : 0.f;
            yv[i] = ok ? yc[(size_t)row * W] : 0.f;
        }
        float sx = 0.f, sy = 0.f, sq = 0.f, sxy = 0.f;
#pragma unroll
        for (int k = 0; k < WIN; ++k) {
            sx += xv[k];
            sy += yv[k];
            sq = fmaf(xv[k], xv[k], fmaf(yv[k], yv[k], sq));
            sxy = fmaf(xv[k], yv[k], sxy);
        }
        cs[0 * AELEM + t] = sx;
        cs[1 * AELEM + t] = sy;
        cs[2 * AELEM + t] = sq;
        cs[3 * AELEM + t] = sxy;
#pragma unroll
        for (int r = 1; r < OUT_H; ++r) {
            const float xn = xv[r + 6], yn = yv[r + 6];
            const float xo = xv[r - 1], yo = yv[r - 1];
            sx += xn - xo;
            sy += yn - yo;
            sq = fmaf(xn, xn, fmaf(yn, yn, fmaf(-xo, xo, fmaf(-yo, yo, sq))));
            sxy = fmaf(xn, yn, fmaf(-xo, yo, sxy));
            const int a = r * PITCH + t;
            cs[0 * AELEM + a] = sx;
            cs[1 * AELEM + a] = sy;
            cs[2 * AELEM + a] = sq;
            cs[3 * AELEM + a] = sxy;
        }
    }
    __syncthreads();

    // ---------- horizontal pass: b128 loads + register sliding ----------
    const int r = t & 15;        // tile row (r==15 idle)
    const int g = t >> 4;        // column group; outputs g*8 .. g*8+7
    const int c0 = g * 8;        // 16B-aligned LDS word offset

    const float C1B = 0.2401f;   // C1 * 49^2
    const float C2B = 2.1168f;   // C2 * 48*49

    float acc = 0.f;
    if (r < OUT_H && (y0 + r) < OH) {
        float S[4][8];
#pragma unroll
        for (int a = 0; a < 4; ++a) {
            const float* bp = &cs[a * AELEM + r * PITCH + c0];
            const float4 q0 = *(const float4*)(bp);
            const float4 q1 = *(const float4*)(bp + 4);
            const float4 q2 = *(const float4*)(bp + 8);
            const float4 q3 = *(const float4*)(bp + 12);
            const float v[16] = {q0.x, q0.y, q0.z, q0.w, q1.x, q1.y, q1.z, q1.w,
                                 q2.x, q2.y, q2.z, q2.w, q3.x, q3.y, q3.z, q3.w};
            float s = ((v[0] + v[1]) + (v[2] + v[3])) + ((v[4] + v[5]) + v[6]);
            S[a][0] = s;
#pragma unroll
            for (int j = 1; j < 8; ++j) {
                s += v[j + 6] - v[j - 1];
                S[a][j] = s;
            }
        }
        const int nmax = OUT_W - c0;      // 8 for groups 0..14, 6 for group 15
#pragma unroll
        for (int j = 0; j < 8; ++j) {
            const float Sx = S[0][j], Sy = S[1][j];
            const float Sq = S[2][j], Sxy = S[3][j];
            const float p = Sx * Sy;
            const float qq = fmaf(Sx, Sx, Sy * Sy);
            const float n1 = fmaf(2.f, p, C1B);
            const float n2 = fmaf(98.f, Sxy, fmaf(-2.f, p, C2B));
            const float d1 = qq + C1B;
            const float d2 = fmaf(49.f, Sq, C2B - qq);
            const float s = (n1 * n2) * __builtin_amdgcn_rcpf(d1 * d2);
            acc = (j < nmax) ? acc + s : acc;   // select, don't scale (garbage may be NaN)
        }
    }

    // ---------- block reduction ----------
    const float wsum = wave_reduce(acc);
    if ((t & 63) == 0) red[t >> 6] = wsum;
    __syncthreads();
    if (t == 0) {
        partials[blockIdx.x + TX * (blockIdx.y + TY * blockIdx.z)] =
            red[0] + red[1] + red[2] + red[3];
    }
}

__global__ __launch_bounds__(1024) void ssim_finalize(const float* __restrict__ partials,
                                                      float* __restrict__ out) {
    __shared__ double red[1024];
    const int t = threadIdx.x;
    double s = 0.0;
    for (int i = t; i < NBLK; i += 1024) s += (double)partials[i];
    red[t] = s;
    __syncthreads();
#pragma unroll
    for (int off = 512; off > 0; off >>= 1) {
        if (t < off) red[t] += red[t + off];
        __syncthreads();
    }
    if (t == 0) out[0] = (float)(red[0] / ((double)NIMG * OH * OW));
}

extern "C" void kernel_launch(void* const* d_in, const int* in_sizes, int n_in,
                              void* d_out, int out_size, void* d_ws, size_t ws_size,
                              hipStream_t stream) {
    const float* pred = (const float*)d_in[0];
    const float* act  = (const float*)d_in[1];
    float* partials = (float*)d_ws;              // NBLK floats, fully overwritten each call
    dim3 grid(TX, TY, NIMG);
    ssim_main<<<grid, 256, 0, stream>>>(pred, act, partials);
    ssim_finalize<<<1, 1024, 0, stream>>>(partials, (float*)d_out);
}